// Round 8
// baseline (40.190 us; speedup 1.0000x reference)
//
#include <hip/hip_runtime.h>
#include <hip/hip_fp16.h>
#include <math.h>

#define BB 16
#define CC 3
#define HH 512
#define WW 512
#define HW (HH * WW)
#define RAD 5
#define SEGV 16
#define NSEG (HH / SEGV)            // 32 segments per image
#define NSTRIP 5                    // 5 overlapping 128-col strips, 116 valid each
#define STRIPW 116
#define NTASK (BB * NSEG * NSTRIP)  // 2560 wave-tasks
#define NBLK (NTASK / 2)            // 1280 blocks (2 waves each)
#define NITER (SEGV + 2 * RAD)      // 26 row iterations

__device__ __forceinline__ __half2 shfl_h2(__half2 v, int src) {
    union { __half2 h; int i; } u;
    u.h = v;
    u.i = __shfl(u.i, src);
    return u.h;
}

// Vertical-FIRST separable box sum.
// Per row iteration (26): per-lane vertical ring on quantized per-pixel
// d/p/t (no cross-lane ops). Horizontal 11-sum via shuffle tree ONLY on the
// 16 output iterations, operating on completed vertical sums.
// Prefetch depth 2 (12 loads in flight). No LDS/barriers in main loop.
__global__ __launch_bounds__(128) void fused_vfirst(
    const float* __restrict__ pred, const float* __restrict__ target,
    float* __restrict__ ws_sq, float* __restrict__ ws_cos)
{
    __shared__ float red[4];
    const int tid  = threadIdx.x;
    const int wave = tid >> 6, lane = tid & 63;

    // bijective XCD-contiguous swizzle (1280 % 8 == 0)
    const int bid = (int)blockIdx.x;
    const int swz = (bid & 7) * (NBLK / 8) + (bid >> 3);

    const int task  = swz * 2 + wave;
    const int img   = task / (NSEG * NSTRIP);
    const int rem   = task % (NSEG * NSTRIP);
    const int seg   = rem / NSTRIP;
    const int strip = rem - seg * NSTRIP;

    const int y0   = seg * SEGV;
    const int col0 = strip * STRIPW - 6 + lane * 2;      // even
    const int colc = min(max(col0, 0), WW - 2);
    const float mx = (col0 >= 0 && col0 < WW) ? 1.f : 0.f;
    const bool vout = (lane >= 3) && (lane <= 60) && (col0 < WW);

    const long base = (long)img * (CC * HW);

    // ---- prefetch rows it=0,1 into slots 0,1 (depth-2 pipeline) ----
    float2 A0[2], A1[2], A2[2], B0[2], B1[2], B2[2];
    #pragma unroll
    for (int s = 0; s < 2; ++s) {
        const int y  = y0 - RAD + s;
        const int yc = min(max(y, 0), HH - 1);
        const long off = base + (long)yc * WW + colc;
        A0[s] = *(const float2*)(pred + off);
        A1[s] = *(const float2*)(pred + off + HW);
        A2[s] = *(const float2*)(pred + off + 2 * HW);
        B0[s] = *(const float2*)(target + off);
        B1[s] = *(const float2*)(target + off + HW);
        B2[s] = *(const float2*)(target + off + 2 * HW);
    }

    // vertical ring: quantized per-pixel (d,p) for col0, col0+1 and (t0,t1)
    __half2 ringA[11], ringB[11], ringT[11];
    float Vd0=0.f, Vd1=0.f, Vp0=0.f, Vp1=0.f, Vt0=0.f, Vt1=0.f;
    float sq = 0.f, cosacc = 0.f;

    #pragma unroll
    for (int it = 0; it < NITER; ++it) {
        const int y = y0 - RAD + it;
        const float msk = (y >= 0 && y < HH) ? mx : 0.f;
        const int cur = it & 1;                    // compile-time under unroll

        const float2 p0=A0[cur], p1=A1[cur], p2=A2[cur];
        const float2 t0=B0[cur], t1=B1[cur], t2=B2[cur];

        if (it + 2 < NITER) {                      // prefetch row it+2
            const int y2  = y0 - RAD + it + 2;
            const int yc2 = min(max(y2, 0), HH - 1);
            const long off2 = base + (long)yc2 * WW + colc;
            A0[cur] = *(const float2*)(pred + off2);
            A1[cur] = *(const float2*)(pred + off2 + HW);
            A2[cur] = *(const float2*)(pred + off2 + 2 * HW);
            B0[cur] = *(const float2*)(target + off2);
            B1[cur] = *(const float2*)(target + off2 + HW);
            B2[cur] = *(const float2*)(target + off2 + 2 * HW);
        }

        // per-pixel dot/pp/tt, masked (zero padding outside image)
        const float ad = (p0.x*t0.x + p1.x*t1.x + p2.x*t2.x) * msk;
        const float bd = (p0.y*t0.y + p1.y*t1.y + p2.y*t2.y) * msk;
        const float ap = (p0.x*p0.x + p1.x*p1.x + p2.x*p2.x) * msk;
        const float bp = (p0.y*p0.y + p1.y*p1.y + p2.y*p2.y) * msk;
        const float at = (t0.x*t0.x + t1.x*t1.x + t2.x*t2.x) * msk;
        const float bt = (t0.y*t0.y + t1.y*t1.y + t2.y*t2.y) * msk;

        // PSNR squared error: owned rows x valid cols only
        if (it >= RAD && it < RAD + SEGV && vout) {
            const float e0=p0.x-t0.x, e1=p1.x-t1.x, e2=p2.x-t2.x;
            const float f0=p0.y-t0.y, f1=p1.y-t1.y, f2=p2.y-t2.y;
            sq += e0*e0 + e1*e1 + e2*e2 + f0*f0 + f1*f1 + f2*f2;
        }

        // quantize FIRST; accumulate the dequantized values -> later ring
        // subtract of the identical values cancels exactly (no drift)
        const __half2 qA = __floats2half2_rn(ad, ap);   // col0 (d,p)
        const __half2 qB = __floats2half2_rn(bd, bp);   // col1 (d,p)
        const __half2 qT = __floats2half2_rn(at, bt);   // (t0,t1)
        const float2 fA = __half22float2(qA);
        const float2 fB = __half22float2(qB);
        const float2 fT = __half22float2(qT);
        Vd0 += fA.x; Vp0 += fA.y;
        Vd1 += fB.x; Vp1 += fB.y;
        Vt0 += fT.x; Vt1 += fT.y;

        if (it >= 10) {
            // vertical sums complete for output row y-5: horizontal tree
            // packed {d,p} half2 tree: h(2i)=b_{i-3}+S5, h(2i+1)=S5+a_{i+3}
            __half2 h0dp, h1dp;
            {
                const __half2 Pk = __floats2half2_rn(Vd0 + Vd1, Vp0 + Vp1);
                const __half2 Ak = __floats2half2_rn(Vd0, Vp0);
                const __half2 Bk = __floats2half2_rn(Vd1, Vp1);
                const __half2 u1 = __hadd2(Pk, shfl_h2(Pk, lane + 1));
                const __half2 u2 = __hadd2(u1, shfl_h2(u1, lane + 2));
                const __half2 u3 = __hadd2(u2, shfl_h2(Pk, lane + 4));
                const __half2 S5 = shfl_h2(u3, lane - 2);
                h0dp = __hadd2(shfl_h2(Bk, lane - 3), S5);
                h1dp = __hadd2(S5, shfl_h2(Ak, lane + 3));
            }
            float wT0, wT1;
            {
                const float pr = Vt0 + Vt1;
                const float u1 = pr + __shfl(pr, lane + 1);
                const float u2 = u1 + __shfl(u1, lane + 2);
                const float u3 = u2 + __shfl(pr, lane + 4);
                const float S5 = __shfl(u3, lane - 2);
                wT0 = __shfl(Vt1, lane - 3) + S5;
                wT1 = S5 + __shfl(Vt0, lane + 3);
            }
            if (vout) {
                const float2 w0 = __half22float2(h0dp);   // (Wd0, Wp0)
                const float2 w1 = __half22float2(h1dp);
                cosacc += w0.x / (sqrtf(fmaxf(w0.y * wT0, 0.f)) + 1e-6f);
                cosacc += w1.x / (sqrtf(fmaxf(w1.y * wT1, 0.f)) + 1e-6f);
            }
            // retire the row leaving the vertical window
            const float2 oA = __half22float2(ringA[(it + 1) % 11]);
            const float2 oB = __half22float2(ringB[(it + 1) % 11]);
            const float2 oT = __half22float2(ringT[(it + 1) % 11]);
            Vd0 -= oA.x; Vp0 -= oA.y;
            Vd1 -= oB.x; Vp1 -= oB.y;
            Vt0 -= oT.x; Vt1 -= oT.y;
        }
        ringA[it % 11] = qA;
        ringB[it % 11] = qB;
        ringT[it % 11] = qT;
    }

    // wave reduce -> block partials
    #pragma unroll
    for (int o = 32; o > 0; o >>= 1) {
        cosacc += __shfl_down(cosacc, o);
        sq     += __shfl_down(sq, o);
    }
    if (lane == 0) { red[wave] = cosacc; red[wave + 2] = sq; }
    __syncthreads();
    if (tid == 0) {
        ws_cos[swz] = red[0] + red[1];
        ws_sq [swz] = red[2] + red[3];
    }
}

// ---------------- finalize: 1280 sq + 1280 cos partials ----------------
__global__ __launch_bounds__(256) void finalize4(
    const float* __restrict__ ws_sq, const float* __restrict__ ws_cos,
    float* __restrict__ out)
{
    __shared__ float sq_b[16];
    __shared__ float cred[4];
    const int tid = threadIdx.x;

    // sq: 80 partials per image; 16 threads/image, 5 values each
    const int b = tid >> 4, j = tid & 15;
    float s = 0.f;
    #pragma unroll
    for (int k = 0; k < 5; ++k) s += ws_sq[b * 80 + j * 5 + k];
    #pragma unroll
    for (int o = 8; o > 0; o >>= 1) s += __shfl_down(s, o, 16);
    if (j == 0) sq_b[b] = s;

    float c = 0.f;
    #pragma unroll
    for (int k = 0; k < 5; ++k) c += ws_cos[tid + 256 * k];
    #pragma unroll
    for (int o = 32; o > 0; o >>= 1) c += __shfl_down(c, o);
    if ((tid & 63) == 0) cred[tid >> 6] = c;
    __syncthreads();

    if (tid == 0) {
        const float csum = cred[0] + cred[1] + cred[2] + cred[3];
        const float scale = 4.342944819032518f;   // 10 / ln(10)
        float lsum = 0.f;
        for (int bb = 0; bb < 16; ++bb)
            lsum += logf(sq_b[bb] / (float)(CC * HW) + 1e-8f);
        out[0] = scale * (lsum / (float)BB) + (1.f - csum / (float)(BB * HW));
    }
}

extern "C" void kernel_launch(void* const* d_in, const int* in_sizes, int n_in,
                              void* d_out, int out_size, void* d_ws, size_t ws_size,
                              hipStream_t stream)
{
    const float* pred   = (const float*)d_in[0];
    const float* target = (const float*)d_in[1];

    float* ws_sq  = (float*)d_ws;                        // 1280 floats
    float* ws_cos = (float*)((char*)d_ws + 8192);        // 1280 floats

    fused_vfirst<<<dim3(NBLK), 128, 0, stream>>>(pred, target, ws_sq, ws_cos);
    finalize4<<<1, 256, 0, stream>>>(ws_sq, ws_cos, (float*)d_out);
}

// Round 9
// 39.885 us; speedup vs baseline: 1.0076x; 1.0076x over previous
//
#include <hip/hip_runtime.h>
#include <hip/hip_fp16.h>
#include <math.h>

#define BB 16
#define CC 3
#define HH 512
#define WW 512
#define HW (HH * WW)
#define RAD 5
#define SEGV 16
#define NSEG (HH / SEGV)            // 32 segments per image
#define NSTRIP 5                    // 5 overlapping 128-col strips, 116 valid each
#define STRIPW 116
#define NTASK (BB * NSEG * NSTRIP)  // 2560 wave-tasks
#define NBLK (NTASK / 2)            // 1280 blocks (2 waves each)
#define NITER (SEGV + 2 * RAD)      // 26 row iterations
#define NSTEP (NITER / 2)           // 13 двух-row steps

__device__ __forceinline__ __half2 shfl_h2(__half2 v, int src) {
    union { __half2 h; int i; } u;
    u.h = v;
    u.i = __shfl(u.i, src);
    return u.h;
}

// R7 body (horizontal-first, packed half2 trees, exact-cancellation fp16
// vertical ring) with a 2-row step: 12 loads (~6 KB/wave) issued per step,
// consumed 2 steps later -> ~800 cycles of latency cover. No LDS/barriers
// in the main loop.
__global__ __launch_bounds__(128) void fused_shfl2(
    const float* __restrict__ pred, const float* __restrict__ target,
    float* __restrict__ ws_sq, float* __restrict__ ws_cos)
{
    __shared__ float red[4];
    const int tid  = threadIdx.x;
    const int wave = tid >> 6, lane = tid & 63;

    // bijective XCD-contiguous swizzle (1280 % 8 == 0)
    const int bid = (int)blockIdx.x;
    const int swz = (bid & 7) * (NBLK / 8) + (bid >> 3);

    const int task  = swz * 2 + wave;
    const int img   = task / (NSEG * NSTRIP);
    const int rem   = task % (NSEG * NSTRIP);
    const int seg   = rem / NSTRIP;
    const int strip = rem - seg * NSTRIP;

    const int y0   = seg * SEGV;
    const int col0 = strip * STRIPW - 6 + lane * 2;      // even
    const int colc = min(max(col0, 0), WW - 2);
    const float mx = (col0 >= 0 && col0 < WW) ? 1.f : 0.f;
    const bool vout = (lane >= 3) && (lane <= 60) && (col0 < WW);

    const long base = (long)img * (CC * HW);

#define LOADROW(D, Y) do { \
        const int yc_ = min(max((Y), 0), HH - 1); \
        const long off_ = base + (long)yc_ * WW + colc; \
        D[0] = *(const float2*)(pred + off_); \
        D[1] = *(const float2*)(pred + off_ + HW); \
        D[2] = *(const float2*)(pred + off_ + 2 * HW); \
        D[3] = *(const float2*)(target + off_); \
        D[4] = *(const float2*)(target + off_ + HW); \
        D[5] = *(const float2*)(target + off_ + 2 * HW); \
    } while (0)

    // stage rows 0..3 (two ping-pong pairs)
    float2 RA[6], RB[6], RC[6], RD[6];
    LOADROW(RA, y0 - RAD + 0);
    LOADROW(RB, y0 - RAD + 1);
    LOADROW(RC, y0 - RAD + 2);
    LOADROW(RD, y0 - RAD + 3);

    __half2 ring0[11], ring1[11], ringT[11];
    float Sd0=0.f, Sd1=0.f, Sp0=0.f, Sp1=0.f, St0=0.f, St1=0.f;
    float sq = 0.f, cosacc = 0.f;

#define ROW_BODY(IT, C) do { \
        const int y_ = y0 - RAD + (IT); \
        const float msk = (y_ >= 0 && y_ < HH) ? mx : 0.f; \
        const float2 p0=C[0], p1=C[1], p2=C[2], t0=C[3], t1=C[4], t2=C[5]; \
        const float ad = (p0.x*t0.x + p1.x*t1.x + p2.x*t2.x) * msk; \
        const float bd = (p0.y*t0.y + p1.y*t1.y + p2.y*t2.y) * msk; \
        const float ap = (p0.x*p0.x + p1.x*p1.x + p2.x*p2.x) * msk; \
        const float bp = (p0.y*p0.y + p1.y*p1.y + p2.y*p2.y) * msk; \
        const float at = (t0.x*t0.x + t1.x*t1.x + t2.x*t2.x) * msk; \
        const float bt = (t0.y*t0.y + t1.y*t1.y + t2.y*t2.y) * msk; \
        if ((IT) >= RAD && (IT) < RAD + SEGV && vout) { \
            const float e0=p0.x-t0.x, e1=p1.x-t1.x, e2=p2.x-t2.x; \
            const float g0=p0.y-t0.y, g1=p1.y-t1.y, g2=p2.y-t2.y; \
            sq += e0*e0 + e1*e1 + e2*e2 + g0*g0 + g1*g1 + g2*g2; \
        } \
        __half2 h0dp, h1dp; \
        { \
            const __half2 Pk = __floats2half2_rn(ad + bd, ap + bp); \
            const __half2 Ak = __floats2half2_rn(ad, ap); \
            const __half2 Bk = __floats2half2_rn(bd, bp); \
            const __half2 u1 = __hadd2(Pk, shfl_h2(Pk, lane + 1)); \
            const __half2 u2 = __hadd2(u1, shfl_h2(u1, lane + 2)); \
            const __half2 u3 = __hadd2(u2, shfl_h2(Pk, lane + 4)); \
            const __half2 S5 = shfl_h2(u3, lane - 2); \
            h0dp = __hadd2(shfl_h2(Bk, lane - 3), S5); \
            h1dp = __hadd2(S5, shfl_h2(Ak, lane + 3)); \
        } \
        __half2 hT; \
        { \
            const float pr = at + bt; \
            const float u1 = pr + __shfl(pr, lane + 1); \
            const float u2 = u1 + __shfl(u1, lane + 2); \
            const float u3 = u2 + __shfl(pr, lane + 4); \
            const float S5 = __shfl(u3, lane - 2); \
            hT = __floats2half2_rn(__shfl(bt, lane - 3) + S5, \
                                   S5 + __shfl(at, lane + 3)); \
        } \
        const float2 f0v = __half22float2(h0dp); \
        const float2 f1v = __half22float2(h1dp); \
        const float2 fTv = __half22float2(hT); \
        Sd0 += f0v.x; Sp0 += f0v.y; \
        Sd1 += f1v.x; Sp1 += f1v.y; \
        St0 += fTv.x; St1 += fTv.y; \
        if ((IT) >= 10) { \
            if (vout) { \
                cosacc += Sd0 / (sqrtf(fmaxf(Sp0 * St0, 0.f)) + 1e-6f); \
                cosacc += Sd1 / (sqrtf(fmaxf(Sp1 * St1, 0.f)) + 1e-6f); \
            } \
            const float2 o0 = __half22float2(ring0[((IT) + 1) % 11]); \
            const float2 o1 = __half22float2(ring1[((IT) + 1) % 11]); \
            const float2 oT = __half22float2(ringT[((IT) + 1) % 11]); \
            Sd0 -= o0.x; Sp0 -= o0.y; \
            Sd1 -= o1.x; Sp1 -= o1.y; \
            St0 -= oT.x; St1 -= oT.y; \
        } \
        ring0[(IT) % 11] = h0dp; \
        ring1[(IT) % 11] = h1dp; \
        ringT[(IT) % 11] = hT; \
    } while (0)

    #pragma unroll
    for (int k = 0; k < NSTEP; ++k) {
        if ((k & 1) == 0) {
            float2 c0[6], c1[6];
            #pragma unroll
            for (int m = 0; m < 6; ++m) { c0[m] = RA[m]; c1[m] = RB[m]; }
            if (2 * k + 4 < NITER) LOADROW(RA, y0 - RAD + 2 * k + 4);
            if (2 * k + 5 < NITER) LOADROW(RB, y0 - RAD + 2 * k + 5);
            ROW_BODY(2 * k,     c0);
            ROW_BODY(2 * k + 1, c1);
        } else {
            float2 c0[6], c1[6];
            #pragma unroll
            for (int m = 0; m < 6; ++m) { c0[m] = RC[m]; c1[m] = RD[m]; }
            if (2 * k + 4 < NITER) LOADROW(RC, y0 - RAD + 2 * k + 4);
            if (2 * k + 5 < NITER) LOADROW(RD, y0 - RAD + 2 * k + 5);
            ROW_BODY(2 * k,     c0);
            ROW_BODY(2 * k + 1, c1);
        }
    }

    // wave reduce -> block partials
    #pragma unroll
    for (int o = 32; o > 0; o >>= 1) {
        cosacc += __shfl_down(cosacc, o);
        sq     += __shfl_down(sq, o);
    }
    if (lane == 0) { red[wave] = cosacc; red[wave + 2] = sq; }
    __syncthreads();
    if (tid == 0) {
        ws_cos[swz] = red[0] + red[1];
        ws_sq [swz] = red[2] + red[3];
    }
}

// ---------------- finalize: 1280 sq + 1280 cos partials ----------------
__global__ __launch_bounds__(256) void finalize4(
    const float* __restrict__ ws_sq, const float* __restrict__ ws_cos,
    float* __restrict__ out)
{
    __shared__ float sq_b[16];
    __shared__ float cred[4];
    const int tid = threadIdx.x;

    // sq: 80 partials per image; 16 threads/image, 5 values each
    const int b = tid >> 4, j = tid & 15;
    float s = 0.f;
    #pragma unroll
    for (int k = 0; k < 5; ++k) s += ws_sq[b * 80 + j * 5 + k];
    #pragma unroll
    for (int o = 8; o > 0; o >>= 1) s += __shfl_down(s, o, 16);
    if (j == 0) sq_b[b] = s;

    float c = 0.f;
    #pragma unroll
    for (int k = 0; k < 5; ++k) c += ws_cos[tid + 256 * k];
    #pragma unroll
    for (int o = 32; o > 0; o >>= 1) c += __shfl_down(c, o);
    if ((tid & 63) == 0) cred[tid >> 6] = c;
    __syncthreads();

    if (tid == 0) {
        const float csum = cred[0] + cred[1] + cred[2] + cred[3];
        const float scale = 4.342944819032518f;   // 10 / ln(10)
        float lsum = 0.f;
        for (int bb = 0; bb < 16; ++bb)
            lsum += logf(sq_b[bb] / (float)(CC * HW) + 1e-8f);
        out[0] = scale * (lsum / (float)BB) + (1.f - csum / (float)(BB * HW));
    }
}

extern "C" void kernel_launch(void* const* d_in, const int* in_sizes, int n_in,
                              void* d_out, int out_size, void* d_ws, size_t ws_size,
                              hipStream_t stream)
{
    const float* pred   = (const float*)d_in[0];
    const float* target = (const float*)d_in[1];

    float* ws_sq  = (float*)d_ws;                        // 1280 floats
    float* ws_cos = (float*)((char*)d_ws + 8192);        // 1280 floats

    fused_shfl2<<<dim3(NBLK), 128, 0, stream>>>(pred, target, ws_sq, ws_cos);
    finalize4<<<1, 256, 0, stream>>>(ws_sq, ws_cos, (float*)d_out);
}